// Round 8
// baseline (698.294 us; speedup 1.0000x reference)
//
#include <hip/hip_runtime.h>
#include <math.h>

// EntNet forward on MI355X.
// Sizes: VOC=32000, MEM=128, NSLOTS=20, NSENT=128, MAXLEN=32, QLEN=16, ANSLEN=8, B=64
//
// R7 post-mortem: 6000 cyc/step, no pipe >60% on the 20 busy CUs ->
// latency/barrier-bound at 2 waves/SIMD. R8: wave specialization at 1024 thr
// (4 waves/SIMD): waves 0-7 = MFMA tile + update (R7 structure, no gate);
// waves 8-15 = gate + global prefetch. Shorter phases, 2x TLP, MFMA split
// into 2 independent 12-deep chains. VGPR cap at 1024thr/1blk = 128; R7's
// union of both roles measured 88, split roles + extra acc chain ~100-120.
// Spill tripwire: WRITE_SIZE (640KB clean; MBs = scratch).

typedef __attribute__((ext_vector_type(8)))  short bf16x8;
typedef __attribute__((ext_vector_type(16))) float f32x16;

__device__ __forceinline__ unsigned short f2bh(float x) {   // f32 -> bf16 RNE
    unsigned int u = __float_as_uint(x);
    u += 0x7FFFu + ((u >> 16) & 1u);
    return (unsigned short)(u >> 16);
}
__device__ __forceinline__ float bh2f(unsigned short h) {
    return __uint_as_float(((unsigned int)h) << 16);
}
// packed word w = hi16|lo16 ; value = f(hi) + f(lo); hi = TRUNCATED bf16,
// lo = RNE bf16 of the residual (absorbs truncation error; recon ~2^-16 |x|)
__device__ __forceinline__ float unpack_w(unsigned int w) {
    return __uint_as_float(w & 0xFFFF0000u) + __uint_as_float(w << 16);
}
__device__ __forceinline__ unsigned int pack_w(float x) {
    const unsigned int hi = __float_as_uint(x) & 0xFFFF0000u;
    const float res = x - __uint_as_float(hi);
    return hi | (unsigned int)f2bh(res);
}

// ---------------------------------------------------------------- prep
__global__ __launch_bounds__(128) void prep_kernel(
    const int* __restrict__ ids, const int* __restrict__ ques, const int* __restrict__ ans,
    const float* __restrict__ E, const float* __restrict__ Ww, const float* __restrict__ Wb,
    const float* __restrict__ Vw, const float* __restrict__ Vb, const float* __restrict__ skeys,
    float* __restrict__ sT, float* __restrict__ WsT, float* __restrict__ vkey,
    float* __restrict__ qv, float* __restrict__ a1v, float* __restrict__ a2v,
    float* __restrict__ SK)
{
    const int bi  = blockIdx.x;
    const int tid = threadIdx.x;   // 128
    __shared__ float s_l[8][132];
    __shared__ float sk_l[20 * 132];
    __shared__ float k_l[128];
    if (bi < 1024) {
        const int b = bi >> 4;
        const int g = bi & 15;
        for (int r = tid; r < 2560; r += 128) sk_l[(r >> 7) * 132 + (r & 127)] = skeys[r];
        for (int tt = 0; tt < 8; ++tt) {
            const int t     = g * 8 + tt;
            const int token = ids[b * 4096 + t];
            const float v   = E[token * 128 + tid];
            s_l[tt][tid] = v;
            sT[(t * 64 + b) * 128 + tid] = v;         // layout (t, b, m)
        }
        __syncthreads();
        // Ws rows
        float acc[8];
        const float wbn = Wb[tid];
        #pragma unroll
        for (int i = 0; i < 8; ++i) acc[i] = wbn;
        const float4* wrow = (const float4*)(Ww + tid * 128);
        for (int m4 = 0; m4 < 32; ++m4) {
            const float4 w = wrow[m4];
            #pragma unroll
            for (int tt = 0; tt < 8; ++tt) {
                acc[tt] += s_l[tt][m4*4+0]*w.x + s_l[tt][m4*4+1]*w.y
                         + s_l[tt][m4*4+2]*w.z + s_l[tt][m4*4+3]*w.w;
            }
        }
        for (int tt = 0; tt < 8; ++tt)
            WsT[((g*8+tt) * 64 + b) * 128 + tid] = acc[tt];     // layout (t, b, n)
        // SK[j][t][b] = dot(s_t[b], skeys[j])  (gate key-dot, hoisted from scan)
        for (int idx = tid; idx < 160; idx += 128) {
            const int tt = idx / 20;
            const int jj = idx - tt * 20;
            float d = 0.f;
            for (int m = 0; m < 128; ++m) d += s_l[tt][m] * sk_l[jj * 132 + m];
            SK[(jj * 128 + (g*8 + tt)) * 64 + b] = d;
        }
    } else if (bi < 1044) {
        const int j = bi - 1024;
        k_l[tid] = skeys[j * 128 + tid];
        __syncthreads();
        float acc = Vb[tid];
        const float4* vrow = (const float4*)(Vw + tid * 128);
        for (int m4 = 0; m4 < 32; ++m4) {
            const float4 w = vrow[m4];
            acc += k_l[m4*4]*w.x + k_l[m4*4+1]*w.y + k_l[m4*4+2]*w.z + k_l[m4*4+3]*w.w;
        }
        vkey[j * 128 + tid] = acc;
    } else {
        const int b = bi - 1044;
        float sq = 0.f, s1 = 0.f, s2 = 0.f;
        for (int i = 0; i < 16; ++i) sq += E[ques[b*16+i] * 128 + tid];
        for (int i = 0; i < 8;  ++i) s1 += E[ans[(b*8+i)*2+0] * 128 + tid];
        for (int i = 0; i < 8;  ++i) s2 += E[ans[(b*8+i)*2+1] * 128 + tid];
        qv [b*128+tid] = sq * (1.f/16.f);
        a1v[b*128+tid] = s1 * 0.125f;
        a2v[b*128+tid] = s2 * 0.125f;
    }
}

// ---------------------------------------------------------------- scan (specialized waves)
// One block per slot j. 1024 threads = 16 waves, 4 waves/SIMD.
// Waves 0-7 (compute): one 32x32 C tile each (bt2 = wave&1, nt2 = wave>>1).
//   B operand (weights, hi/lo bf16) in 64 VGPRs; A from packed LDS AP
//   (hi16|lo16 of U[b][m], stride 132); 3 MFMAs/kc split into 2 indep chains.
//   Phase2: update owned cells (xprev in regs), write AP, wsv prefetch, ssq.
// Waves 8-15 (gate): g[b] = sigmoid(inv*dot(s_t[b],U[b]) + SK[j][t][b]);
//   phase2: prefetch sv/skv for t+1.
// inv_s: all waves read wred at TOP of step (post-B2 of prev step); writers
// (compute, phase2) are separated from readers by B1. 2 barriers/step.
// C/D layout [m74/m101]: col = lane&31, row = (reg&3)+8*(reg>>2)+4*(lane>>5).
__global__ __launch_bounds__(1024, 1) void scan_kernel(
    const float* __restrict__ sT, const float* __restrict__ WsT,
    const float* __restrict__ vkey, const float* __restrict__ Uw,
    const float* __restrict__ Ub, const float* __restrict__ SK,
    float* __restrict__ h_out)
{
    __shared__ unsigned int AP[64 * 132];   // packed state, stride 132
    __shared__ float g_l[64];
    __shared__ float wred[8];

    const int j    = blockIdx.x;
    const int tid  = threadIdx.x;        // 1024
    const int wave = tid >> 6;           // 0..15
    const int lane = tid & 63;
    const bool is_compute = (wave < 8);

    // compute-wave coords
    const int l32  = lane & 31;
    const int q    = lane >> 5;          // 0..1
    const int bt2  = wave & 1;           // b half
    const int nt2  = (wave >> 1) & 3;    // n quarter
    const int n    = nt2 * 32 + l32;     // owned output column

    // gate-wave coords
    const int gtid = tid - 512;          // 0..511 for gate waves
    const int gb   = (gtid >> 3) & 63;   // gate: batch row
    const int gm   = (gtid & 7) * 16;    // gate: m-slice (16 words)

    // ---- one-time init ----
    bf16x8 b_h[8], b_l[8];
    float  ubv = 0.f;
    if (is_compute) {
        const int k0 = q * 8;
        #pragma unroll
        for (int kc = 0; kc < 8; ++kc) {
            const float4* src = (const float4*)(Uw + n * 128 + kc * 16 + k0);
            const float4 v0 = src[0], v1 = src[1];
            const float xs[8] = {v0.x,v0.y,v0.z,v0.w, v1.x,v1.y,v1.z,v1.w};
            #pragma unroll
            for (int e = 0; e < 8; ++e) {
                const unsigned short h = f2bh(xs[e]);
                b_h[kc][e] = (short)h;
                b_l[kc][e] = (short)f2bh(xs[e] - bh2f(h));
            }
        }
        ubv = Ub[n] + vkey[j * 128 + n];
    }
    for (int i = tid; i < 64 * 132; i += 1024) AP[i] = 0u;
    if (tid < 8) wred[tid] = 0.125f;     // sum = 1 -> first inv_s = 1 (unused: U=0)

    // per-role pipelined registers
    float xprev[16];
    float wsv[16];
    float4 sv0, sv1, sv2, sv3;
    float  skv = 0.f;
    if (is_compute) {
        #pragma unroll
        for (int r = 0; r < 16; ++r) {
            xprev[r] = 0.f;
            const int brow = bt2*32 + 4*q + (r & 3) + 8*(r >> 2);
            wsv[r] = WsT[(0*64 + brow)*128 + n];
        }
    } else {
        const float4* s4 = (const float4*)(sT + (0*64 + gb)*128 + gm);
        sv0 = s4[0]; sv1 = s4[1]; sv2 = s4[2]; sv3 = s4[3];
        skv = SK[(j*128 + 0)*64 + gb];
    }
    __syncthreads();

    for (int t = 0; t < 128; ++t) {
        // ---- all waves: inv_s from wred (written pre-B2 of prev step) ----
        const float4 w0 = *(const float4*)(wred);
        const float4 w1 = *(const float4*)(wred + 4);
        const float inv_s = 1.f / sqrtf(w0.x+w0.y+w0.z+w0.w + w1.x+w1.y+w1.z+w1.w);

        f32x16 acc0 = {0.f,0.f,0.f,0.f,0.f,0.f,0.f,0.f,
                       0.f,0.f,0.f,0.f,0.f,0.f,0.f,0.f};
        f32x16 acc1 = acc0;
        if (is_compute) {
            // ---- MFMA: acc = U(32b x 128m) . W(32n x 128m)^T, 2 indep chains ----
            const int arow = (bt2*32 + l32) * 132;
            const int k0   = q * 8;
            #pragma unroll
            for (int kc = 0; kc < 8; ++kc) {
                const uint4 p0 = *(const uint4*)(AP + arow + kc*16 + k0);
                const uint4 p1 = *(const uint4*)(AP + arow + kc*16 + k0 + 4);
                bf16x8 ah, al;
                unsigned int* ahd = (unsigned int*)&ah;
                unsigned int* ald = (unsigned int*)&al;
                ahd[0] = __builtin_amdgcn_perm(p0.y, p0.x, 0x07060302u);
                ald[0] = __builtin_amdgcn_perm(p0.y, p0.x, 0x05040100u);
                ahd[1] = __builtin_amdgcn_perm(p0.w, p0.z, 0x07060302u);
                ald[1] = __builtin_amdgcn_perm(p0.w, p0.z, 0x05040100u);
                ahd[2] = __builtin_amdgcn_perm(p1.y, p1.x, 0x07060302u);
                ald[2] = __builtin_amdgcn_perm(p1.y, p1.x, 0x05040100u);
                ahd[3] = __builtin_amdgcn_perm(p1.w, p1.z, 0x07060302u);
                ald[3] = __builtin_amdgcn_perm(p1.w, p1.z, 0x05040100u);
                if (kc & 1) {
                    acc1 = __builtin_amdgcn_mfma_f32_32x32x16_bf16(ah, b_h[kc], acc1, 0, 0, 0);
                    acc1 = __builtin_amdgcn_mfma_f32_32x32x16_bf16(ah, b_l[kc], acc1, 0, 0, 0);
                    acc1 = __builtin_amdgcn_mfma_f32_32x32x16_bf16(al, b_h[kc], acc1, 0, 0, 0);
                } else {
                    acc0 = __builtin_amdgcn_mfma_f32_32x32x16_bf16(ah, b_h[kc], acc0, 0, 0, 0);
                    acc0 = __builtin_amdgcn_mfma_f32_32x32x16_bf16(ah, b_l[kc], acc0, 0, 0, 0);
                    acc0 = __builtin_amdgcn_mfma_f32_32x32x16_bf16(al, b_h[kc], acc0, 0, 0, 0);
                }
            }
        } else {
            // ---- gate: g[b] = sigmoid(inv*dot(s_t[b],U[b]) + SK) ----
            const uint4* u4 = (const uint4*)(AP + gb * 132 + gm);
            const uint4 uw0 = u4[0], uw1 = u4[1], uw2 = u4[2], uw3 = u4[3];
            float d1 = sv0.x*unpack_w(uw0.x) + sv0.y*unpack_w(uw0.y)
                     + sv0.z*unpack_w(uw0.z) + sv0.w*unpack_w(uw0.w)
                     + sv1.x*unpack_w(uw1.x) + sv1.y*unpack_w(uw1.y)
                     + sv1.z*unpack_w(uw1.z) + sv1.w*unpack_w(uw1.w)
                     + sv2.x*unpack_w(uw2.x) + sv2.y*unpack_w(uw2.y)
                     + sv2.z*unpack_w(uw2.z) + sv2.w*unpack_w(uw2.w)
                     + sv3.x*unpack_w(uw3.x) + sv3.y*unpack_w(uw3.y)
                     + sv3.z*unpack_w(uw3.z) + sv3.w*unpack_w(uw3.w);
            d1 += __shfl_xor(d1, 1, 64);
            d1 += __shfl_xor(d1, 2, 64);
            d1 += __shfl_xor(d1, 4, 64);
            if ((gtid & 7) == 0) g_l[gb] = 1.f / (1.f + expf(-(inv_s * d1 + skv)));
        }
        __syncthreads();   // B1: AP/wred reads + g_l writes complete

        if (is_compute) {
            // ---- update owned (b, n) cells in C layout ----
            const float4 gA = *(const float4*)(g_l + bt2*32 + 4*q + 0);
            const float4 gB = *(const float4*)(g_l + bt2*32 + 4*q + 8);
            const float4 gC = *(const float4*)(g_l + bt2*32 + 4*q + 16);
            const float4 gD = *(const float4*)(g_l + bt2*32 + 4*q + 24);
            const float gr[16] = {gA.x,gA.y,gA.z,gA.w, gB.x,gB.y,gB.z,gB.w,
                                  gC.x,gC.y,gC.z,gC.w, gD.x,gD.y,gD.z,gD.w};
            float ssq = 0.f;
            #pragma unroll
            for (int r = 0; r < 16; ++r) {
                const int brow = bt2*32 + 4*q + (r & 3) + 8*(r >> 2);
                float hr = fmaf(inv_s, acc0[r] + acc1[r], ubv + wsv[r]);
                hr = fmaxf(hr, 0.f);                          // h_cand
                const float x = fmaf(inv_s, xprev[r], gr[r] * hr);
                xprev[r] = x;
                AP[brow*132 + n] = pack_w(x);
                ssq = fmaf(x, x, ssq);
            }
            // prefetch Ws for t+1 (drains at B2)
            {
                const int tn = (t < 127) ? t + 1 : 0;
                #pragma unroll
                for (int r = 0; r < 16; ++r) {
                    const int brow = bt2*32 + 4*q + (r & 3) + 8*(r >> 2);
                    wsv[r] = WsT[(tn*64 + brow)*128 + n];
                }
            }
            #pragma unroll
            for (int m = 1; m < 64; m <<= 1) ssq += __shfl_xor(ssq, m, 64);
            if (lane == 0) wred[wave] = ssq;
        } else {
            // prefetch gate inputs for t+1 (drains at B2)
            const int tn = (t < 127) ? t + 1 : 0;
            const float4* s4 = (const float4*)(sT + (tn*64 + gb)*128 + gm);
            sv0 = s4[0]; sv1 = s4[1]; sv2 = s4[2]; sv3 = s4[3];
            skv = SK[(j*128 + tn)*64 + gb];
        }
        __syncthreads();   // B2: AP writes + wred partials visible; prefetch drained
    }

    // ---- h = inv * state, layout (b, j, m) ----
    const float4 w0 = *(const float4*)(wred);
    const float4 w1 = *(const float4*)(wred + 4);
    const float inv_f = 1.f / sqrtf(w0.x+w0.y+w0.z+w0.w + w1.x+w1.y+w1.z+w1.w);
    if (is_compute) {
        #pragma unroll
        for (int r = 0; r < 16; ++r) {
            const int brow = bt2*32 + 4*q + (r & 3) + 8*(r >> 2);
            h_out[(brow*20 + j)*128 + n] = inv_f * xprev[r];
        }
    }
}

// ---------------------------------------------------------------- final
__global__ __launch_bounds__(128) void final_kernel(
    const float* __restrict__ h, const float* __restrict__ qv,
    const float* __restrict__ a1v, const float* __restrict__ a2v,
    const float* __restrict__ Hw, const float* __restrict__ Hb,
    float* __restrict__ out)
{
    const int b   = blockIdx.x;
    const int tid = threadIdx.x;    // 128
    __shared__ float hb[20][128];
    __shared__ float ql[128];
    __shared__ float ul[128];
    __shared__ float pl[20];
    __shared__ float lgt[20];
    __shared__ float red1[2], red2[2];

    for (int jj = 0; jj < 20; ++jj) hb[jj][tid] = h[(b*20+jj)*128 + tid];
    ql[tid] = qv[b*128 + tid];
    __syncthreads();
    if (tid < 20) {
        float d = 0.f;
        for (int m = 0; m < 128; ++m) d += hb[tid][m] * ql[m];
        lgt[tid] = d;
    }
    __syncthreads();
    if (tid == 0) {
        float mx = lgt[0];
        for (int jj = 1; jj < 20; ++jj) mx = fmaxf(mx, lgt[jj]);
        float s = 0.f;
        for (int jj = 0; jj < 20; ++jj) { const float e = expf(lgt[jj]-mx); pl[jj] = e; s += e; }
        const float is = 1.f / s;
        for (int jj = 0; jj < 20; ++jj) pl[jj] *= is;
    }
    __syncthreads();
    float u = 0.f;
    for (int jj = 0; jj < 20; ++jj) u += pl[jj] * hb[jj][tid];
    ul[tid] = u;
    __syncthreads();
    float acc = ql[tid] + Hb[tid];
    const float4* hwr = (const float4*)(Hw + tid*128);
    for (int m4 = 0; m4 < 32; ++m4) {
        const float4 w = hwr[m4];
        acc += ul[m4*4]*w.x + ul[m4*4+1]*w.y + ul[m4*4+2]*w.z + ul[m4*4+3]*w.w;
    }
    const float r  = fmaxf(acc, 0.f);
    float y1 = r * a1v[b*128+tid];
    float y2 = r * a2v[b*128+tid];
    #pragma unroll
    for (int mask = 1; mask < 64; mask <<= 1) {
        y1 += __shfl_xor(y1, mask, 64);
        y2 += __shfl_xor(y2, mask, 64);
    }
    if ((tid & 63) == 0) { red1[tid>>6] = y1; red2[tid>>6] = y2; }
    __syncthreads();
    if (tid == 0) {
        const float z1 = red1[0] + red1[1];
        const float z2 = red2[0] + red2[1];
        const float mx = fmaxf(z1, z2);
        const float e1 = expf(z1-mx), e2 = expf(z2-mx);
        const float s  = e1 + e2;
        out[b*2+0] = e1 / s;
        out[b*2+1] = e2 / s;
    }
}

// ---------------------------------------------------------------- launch
extern "C" void kernel_launch(void* const* d_in, const int* in_sizes, int n_in,
                              void* d_out, int out_size, void* d_ws, size_t ws_size,
                              hipStream_t stream)
{
    const int*   ids  = (const int*)  d_in[0];
    const int*   ques = (const int*)  d_in[1];
    const int*   ans  = (const int*)  d_in[2];
    const float* E    = (const float*)d_in[3];
    const float* Uw   = (const float*)d_in[4];
    const float* Ubv  = (const float*)d_in[5];
    const float* Vw   = (const float*)d_in[6];
    const float* Vb   = (const float*)d_in[7];
    const float* Ww   = (const float*)d_in[8];
    const float* Wb   = (const float*)d_in[9];
    const float* sk   = (const float*)d_in[10];
    const float* Hw   = (const float*)d_in[11];
    const float* Hb   = (const float*)d_in[12];

    // workspace (floats): sT 1M | WsT 1M | vkey 2560 | qv/a1v/a2v 3*8192 | h 163840 | SK 163840
    float* ws   = (float*)d_ws;
    float* sT   = ws;
    float* WsT  = sT  + 1048576;
    float* vkey = WsT + 1048576;
    float* qv   = vkey + 2560;
    float* a1v  = qv  + 8192;
    float* a2v  = a1v + 8192;
    float* h    = a2v + 8192;
    float* SK   = h   + 163840;

    prep_kernel<<<1108, 128, 0, stream>>>(ids, ques, ans, E, Ww, Wb, Vw, Vb, sk,
                                          sT, WsT, vkey, qv, a1v, a2v, SK);
    scan_kernel<<<20, 1024, 0, stream>>>(sT, WsT, vkey, Uw, Ubv, SK, h);
    final_kernel<<<64, 128, 0, stream>>>(h, qv, a1v, a2v, Hw, Hb, (float*)d_out);
}

// Round 9
// 447.094 us; speedup vs baseline: 1.5619x; 1.5619x over previous
//
#include <hip/hip_runtime.h>
#include <math.h>

// EntNet forward on MI355X.
// Sizes: VOC=32000, MEM=128, NSLOTS=20, NSENT=128, MAXLEN=32, QLEN=16, ANSLEN=8, B=64
//
// Register model (R2/R3/R4/R8 evidence): per-wave budget = 512 regs/SIMD /
// (waves/SIMD), VGPR+AGPR combined. 512thr+1blk -> 2 waves/SIMD -> 256/wave
// (R7 fits at 88+32). 1024thr -> 128/wave -> spills this design (R8: WRITE_SIZE
// 640KB->5.5MB, 595us). So: 512 threads, one block per slot, 20 CUs.
//
// R9 = R7 + (1) prefetch t+1 globals at TOP of step (shadow regs, rotate after
// B2; plain global->VGPR loads are not drained by barriers, so completion
// overlaps the whole step instead of ~60 cyc) + (2) MFMA split into 2
// independent 12-deep chains (kc parity). Everything else identical to R7.

typedef __attribute__((ext_vector_type(8)))  short bf16x8;
typedef __attribute__((ext_vector_type(16))) float f32x16;

__device__ __forceinline__ unsigned short f2bh(float x) {   // f32 -> bf16 RNE
    unsigned int u = __float_as_uint(x);
    u += 0x7FFFu + ((u >> 16) & 1u);
    return (unsigned short)(u >> 16);
}
__device__ __forceinline__ float bh2f(unsigned short h) {
    return __uint_as_float(((unsigned int)h) << 16);
}
// packed word w = hi16|lo16 ; value = f(hi) + f(lo); hi = TRUNCATED bf16,
// lo = RNE bf16 of the residual (absorbs truncation error; recon ~2^-16 |x|)
__device__ __forceinline__ float unpack_w(unsigned int w) {
    return __uint_as_float(w & 0xFFFF0000u) + __uint_as_float(w << 16);
}
__device__ __forceinline__ unsigned int pack_w(float x) {
    const unsigned int hi = __float_as_uint(x) & 0xFFFF0000u;
    const float res = x - __uint_as_float(hi);
    return hi | (unsigned int)f2bh(res);
}

// ---------------------------------------------------------------- prep
__global__ __launch_bounds__(128) void prep_kernel(
    const int* __restrict__ ids, const int* __restrict__ ques, const int* __restrict__ ans,
    const float* __restrict__ E, const float* __restrict__ Ww, const float* __restrict__ Wb,
    const float* __restrict__ Vw, const float* __restrict__ Vb, const float* __restrict__ skeys,
    float* __restrict__ sT, float* __restrict__ WsT, float* __restrict__ vkey,
    float* __restrict__ qv, float* __restrict__ a1v, float* __restrict__ a2v,
    float* __restrict__ SK)
{
    const int bi  = blockIdx.x;
    const int tid = threadIdx.x;   // 128
    __shared__ float s_l[8][132];
    __shared__ float sk_l[20 * 132];
    __shared__ float k_l[128];
    if (bi < 1024) {
        const int b = bi >> 4;
        const int g = bi & 15;
        for (int r = tid; r < 2560; r += 128) sk_l[(r >> 7) * 132 + (r & 127)] = skeys[r];
        for (int tt = 0; tt < 8; ++tt) {
            const int t     = g * 8 + tt;
            const int token = ids[b * 4096 + t];
            const float v   = E[token * 128 + tid];
            s_l[tt][tid] = v;
            sT[(t * 64 + b) * 128 + tid] = v;         // layout (t, b, m)
        }
        __syncthreads();
        // Ws rows
        float acc[8];
        const float wbn = Wb[tid];
        #pragma unroll
        for (int i = 0; i < 8; ++i) acc[i] = wbn;
        const float4* wrow = (const float4*)(Ww + tid * 128);
        for (int m4 = 0; m4 < 32; ++m4) {
            const float4 w = wrow[m4];
            #pragma unroll
            for (int tt = 0; tt < 8; ++tt) {
                acc[tt] += s_l[tt][m4*4+0]*w.x + s_l[tt][m4*4+1]*w.y
                         + s_l[tt][m4*4+2]*w.z + s_l[tt][m4*4+3]*w.w;
            }
        }
        for (int tt = 0; tt < 8; ++tt)
            WsT[((g*8+tt) * 64 + b) * 128 + tid] = acc[tt];     // layout (t, b, n)
        // SK[j][t][b] = dot(s_t[b], skeys[j])  (gate key-dot, hoisted from scan)
        for (int idx = tid; idx < 160; idx += 128) {
            const int tt = idx / 20;
            const int jj = idx - tt * 20;
            float d = 0.f;
            for (int m = 0; m < 128; ++m) d += s_l[tt][m] * sk_l[jj * 132 + m];
            SK[(jj * 128 + (g*8 + tt)) * 64 + b] = d;
        }
    } else if (bi < 1044) {
        const int j = bi - 1024;
        k_l[tid] = skeys[j * 128 + tid];
        __syncthreads();
        float acc = Vb[tid];
        const float4* vrow = (const float4*)(Vw + tid * 128);
        for (int m4 = 0; m4 < 32; ++m4) {
            const float4 w = vrow[m4];
            acc += k_l[m4*4]*w.x + k_l[m4*4+1]*w.y + k_l[m4*4+2]*w.z + k_l[m4*4+3]*w.w;
        }
        vkey[j * 128 + tid] = acc;
    } else {
        const int b = bi - 1044;
        float sq = 0.f, s1 = 0.f, s2 = 0.f;
        for (int i = 0; i < 16; ++i) sq += E[ques[b*16+i] * 128 + tid];
        for (int i = 0; i < 8;  ++i) s1 += E[ans[(b*8+i)*2+0] * 128 + tid];
        for (int i = 0; i < 8;  ++i) s2 += E[ans[(b*8+i)*2+1] * 128 + tid];
        qv [b*128+tid] = sq * (1.f/16.f);
        a1v[b*128+tid] = s1 * 0.125f;
        a2v[b*128+tid] = s2 * 0.125f;
    }
}

// ---------------------------------------------------------------- scan (MFMA 32x32)
// One block per slot j. 512 threads = 8 waves, 2 waves/SIMD (256 regs/wave).
// Each wave owns ONE 32x32 C tile (bt2 = wave&1, nt2 = wave>>1).
//   B operand (weights, hi/lo bf16) in 64 VGPRs, loaded once.
//   A operand from packed LDS AP (hi16|lo16 of U[b][m], stride 132) via v_perm.
//   3 MFMAs/kc (AhBh+AhBl+AlBh, rel err ~2^-16), 2 independent chains.
// C/D layout [m74/m101]: col = lane&31, row = (reg&3)+8*(reg>>2)+4*(lane>>5).
// Globals for step t+1 (sv/skv/wsv) issued at TOP of step t into shadow regs,
// rotated in after B2 -> load latency overlaps the entire step.
// xprev[16] keeps lane-owned state in regs. 2 barriers/step.
__global__ __launch_bounds__(512, 1) void scan_kernel(
    const float* __restrict__ sT, const float* __restrict__ WsT,
    const float* __restrict__ vkey, const float* __restrict__ Uw,
    const float* __restrict__ Ub, const float* __restrict__ SK,
    float* __restrict__ h_out)
{
    __shared__ unsigned int AP[64 * 132];   // packed state, stride 132
    __shared__ float g_l[64];
    __shared__ float wred[8];

    const int j    = blockIdx.x;
    const int tid  = threadIdx.x;        // 512
    const int wave = tid >> 6;           // 0..7
    const int lane = tid & 63;
    const int l32  = lane & 31;
    const int q    = lane >> 5;          // 0..1
    const int bt2  = wave & 1;           // b half
    const int nt2  = wave >> 1;          // n quarter
    const int n    = nt2 * 32 + l32;     // owned output column
    const int gb   = tid >> 3;           // gate: batch row 0..63
    const int gm   = (tid & 7) * 16;     // gate: m-slice (16 words)

    // ---- one-time: weight fragments -> 64 VGPRs ----
    bf16x8 b_h[8], b_l[8];
    {
        const int k0 = q * 8;
        #pragma unroll
        for (int kc = 0; kc < 8; ++kc) {
            const float4* src = (const float4*)(Uw + n * 128 + kc * 16 + k0);
            const float4 v0 = src[0], v1 = src[1];
            const float xs[8] = {v0.x,v0.y,v0.z,v0.w, v1.x,v1.y,v1.z,v1.w};
            #pragma unroll
            for (int e = 0; e < 8; ++e) {
                const unsigned short h = f2bh(xs[e]);
                b_h[kc][e] = (short)h;
                b_l[kc][e] = (short)f2bh(xs[e] - bh2f(h));
            }
        }
    }
    for (int i = tid; i < 64 * 132; i += 512) AP[i] = 0u;
    const float ubv = Ub[n] + vkey[j * 128 + n];

    // lane-owned state rows (C layout), registers across steps
    float xprev[16];
    #pragma unroll
    for (int r = 0; r < 16; ++r) xprev[r] = 0.f;

    // ---- current-step globals (t = 0) ----
    float4 sv0, sv1, sv2, sv3;
    float  skv;
    float  wsv[16];
    {
        const float4* s4 = (const float4*)(sT + (0*64 + gb)*128 + gm);
        sv0 = s4[0]; sv1 = s4[1]; sv2 = s4[2]; sv3 = s4[3];
        skv = SK[(j*128 + 0)*64 + gb];
        #pragma unroll
        for (int r = 0; r < 16; ++r) {
            const int brow = bt2*32 + 4*q + (r & 3) + 8*(r >> 2);
            wsv[r] = WsT[(0*64 + brow)*128 + n];
        }
    }
    __syncthreads();

    float inv_s = 1.f;                   // true mem = inv_s * recon(AP)

    for (int t = 0; t < 128; ++t) {
        // ---- prefetch t+1 into shadow regs (overlaps the whole step) ----
        float4 nv0, nv1, nv2, nv3;
        float  nskv;
        float  nwsv[16];
        {
            const int tn = (t < 127) ? t + 1 : 127;   // t=127 value unused
            const float4* s4 = (const float4*)(sT + (tn*64 + gb)*128 + gm);
            nv0 = s4[0]; nv1 = s4[1]; nv2 = s4[2]; nv3 = s4[3];
            nskv = SK[(j*128 + tn)*64 + gb];
            #pragma unroll
            for (int r = 0; r < 16; ++r) {
                const int brow = bt2*32 + 4*q + (r & 3) + 8*(r >> 2);
                nwsv[r] = WsT[(tn*64 + brow)*128 + n];
            }
        }

        // ---- gate: g[b] = sigmoid(inv*dot(s_t[b],U[b]) + SK[j][t][b]) ----
        {
            const uint4* u4 = (const uint4*)(AP + gb * 132 + gm);
            const uint4 uw0 = u4[0], uw1 = u4[1], uw2 = u4[2], uw3 = u4[3];
            float d1 = sv0.x*unpack_w(uw0.x) + sv0.y*unpack_w(uw0.y)
                     + sv0.z*unpack_w(uw0.z) + sv0.w*unpack_w(uw0.w)
                     + sv1.x*unpack_w(uw1.x) + sv1.y*unpack_w(uw1.y)
                     + sv1.z*unpack_w(uw1.z) + sv1.w*unpack_w(uw1.w)
                     + sv2.x*unpack_w(uw2.x) + sv2.y*unpack_w(uw2.y)
                     + sv2.z*unpack_w(uw2.z) + sv2.w*unpack_w(uw2.w)
                     + sv3.x*unpack_w(uw3.x) + sv3.y*unpack_w(uw3.y)
                     + sv3.z*unpack_w(uw3.z) + sv3.w*unpack_w(uw3.w);
            d1 += __shfl_xor(d1, 1, 64);
            d1 += __shfl_xor(d1, 2, 64);
            d1 += __shfl_xor(d1, 4, 64);
            if ((tid & 7) == 0) g_l[gb] = 1.f / (1.f + expf(-(inv_s * d1 + skv)));
        }

        // ---- MFMA: acc = U(32b x 128m) . W(32n x 128m)^T, 2 indep chains ----
        f32x16 acc0 = {0.f,0.f,0.f,0.f,0.f,0.f,0.f,0.f,
                       0.f,0.f,0.f,0.f,0.f,0.f,0.f,0.f};
        f32x16 acc1 = acc0;
        {
            const int arow = (bt2*32 + l32) * 132;
            const int k0   = q * 8;
            #pragma unroll
            for (int kc = 0; kc < 8; ++kc) {
                const uint4 p0 = *(const uint4*)(AP + arow + kc*16 + k0);
                const uint4 p1 = *(const uint4*)(AP + arow + kc*16 + k0 + 4);
                bf16x8 ah, al;
                unsigned int* ahd = (unsigned int*)&ah;
                unsigned int* ald = (unsigned int*)&al;
                ahd[0] = __builtin_amdgcn_perm(p0.y, p0.x, 0x07060302u);
                ald[0] = __builtin_amdgcn_perm(p0.y, p0.x, 0x05040100u);
                ahd[1] = __builtin_amdgcn_perm(p0.w, p0.z, 0x07060302u);
                ald[1] = __builtin_amdgcn_perm(p0.w, p0.z, 0x05040100u);
                ahd[2] = __builtin_amdgcn_perm(p1.y, p1.x, 0x07060302u);
                ald[2] = __builtin_amdgcn_perm(p1.y, p1.x, 0x05040100u);
                ahd[3] = __builtin_amdgcn_perm(p1.w, p1.z, 0x07060302u);
                ald[3] = __builtin_amdgcn_perm(p1.w, p1.z, 0x05040100u);
                if (kc & 1) {
                    acc1 = __builtin_amdgcn_mfma_f32_32x32x16_bf16(ah, b_h[kc], acc1, 0, 0, 0);
                    acc1 = __builtin_amdgcn_mfma_f32_32x32x16_bf16(ah, b_l[kc], acc1, 0, 0, 0);
                    acc1 = __builtin_amdgcn_mfma_f32_32x32x16_bf16(al, b_h[kc], acc1, 0, 0, 0);
                } else {
                    acc0 = __builtin_amdgcn_mfma_f32_32x32x16_bf16(ah, b_h[kc], acc0, 0, 0, 0);
                    acc0 = __builtin_amdgcn_mfma_f32_32x32x16_bf16(ah, b_l[kc], acc0, 0, 0, 0);
                    acc0 = __builtin_amdgcn_mfma_f32_32x32x16_bf16(al, b_h[kc], acc0, 0, 0, 0);
                }
            }
        }
        __syncthreads();   // B1: AP reads complete; g_l visible

        // ---- update owned (b, n) cells in C layout ----
        const float4 gA = *(const float4*)(g_l + bt2*32 + 4*q + 0);
        const float4 gB = *(const float4*)(g_l + bt2*32 + 4*q + 8);
        const float4 gC = *(const float4*)(g_l + bt2*32 + 4*q + 16);
        const float4 gD = *(const float4*)(g_l + bt2*32 + 4*q + 24);
        const float gr[16] = {gA.x,gA.y,gA.z,gA.w, gB.x,gB.y,gB.z,gB.w,
                              gC.x,gC.y,gC.z,gC.w, gD.x,gD.y,gD.z,gD.w};
        float ssq = 0.f;
        #pragma unroll
        for (int r = 0; r < 16; ++r) {
            const int brow = bt2*32 + 4*q + (r & 3) + 8*(r >> 2);
            float hr = fmaf(inv_s, acc0[r] + acc1[r], ubv + wsv[r]);
            hr = fmaxf(hr, 0.f);                          // h_cand
            const float x = fmaf(inv_s, xprev[r], gr[r] * hr);
            xprev[r] = x;
            AP[brow*132 + n] = pack_w(x);
            ssq = fmaf(x, x, ssq);
        }
        #pragma unroll
        for (int m = 1; m < 64; m <<= 1) ssq += __shfl_xor(ssq, m, 64);
        if (lane == 0) wred[wave] = ssq;
        __syncthreads();   // B2: AP writes + wred partials visible
        const float4 w0 = *(const float4*)(wred);
        const float4 w1 = *(const float4*)(wred + 4);
        inv_s = 1.f / sqrtf(w0.x+w0.y+w0.z+w0.w + w1.x+w1.y+w1.z+w1.w);

        // ---- rotate shadow -> current (first use of prefetched regs) ----
        sv0 = nv0; sv1 = nv1; sv2 = nv2; sv3 = nv3; skv = nskv;
        #pragma unroll
        for (int r = 0; r < 16; ++r) wsv[r] = nwsv[r];
    }

    // ---- h = inv * state, layout (b, j, m) ----
    #pragma unroll
    for (int r = 0; r < 16; ++r) {
        const int brow = bt2*32 + 4*q + (r & 3) + 8*(r >> 2);
        h_out[(brow*20 + j)*128 + n] = inv_s * xprev[r];
    }
}

// ---------------------------------------------------------------- final
__global__ __launch_bounds__(128) void final_kernel(
    const float* __restrict__ h, const float* __restrict__ qv,
    const float* __restrict__ a1v, const float* __restrict__ a2v,
    const float* __restrict__ Hw, const float* __restrict__ Hb,
    float* __restrict__ out)
{
    const int b   = blockIdx.x;
    const int tid = threadIdx.x;    // 128
    __shared__ float hb[20][128];
    __shared__ float ql[128];
    __shared__ float ul[128];
    __shared__ float pl[20];
    __shared__ float lgt[20];
    __shared__ float red1[2], red2[2];

    for (int jj = 0; jj < 20; ++jj) hb[jj][tid] = h[(b*20+jj)*128 + tid];
    ql[tid] = qv[b*128 + tid];
    __syncthreads();
    if (tid < 20) {
        float d = 0.f;
        for (int m = 0; m < 128; ++m) d += hb[tid][m] * ql[m];
        lgt[tid] = d;
    }
    __syncthreads();
    if (tid == 0) {
        float mx = lgt[0];
        for (int jj = 1; jj < 20; ++jj) mx = fmaxf(mx, lgt[jj]);
        float s = 0.f;
        for (int jj = 0; jj < 20; ++jj) { const float e = expf(lgt[jj]-mx); pl[jj] = e; s += e; }
        const float is = 1.f / s;
        for (int jj = 0; jj < 20; ++jj) pl[jj] *= is;
    }
    __syncthreads();
    float u = 0.f;
    for (int jj = 0; jj < 20; ++jj) u += pl[jj] * hb[jj][tid];
    ul[tid] = u;
    __syncthreads();
    float acc = ql[tid] + Hb[tid];
    const float4* hwr = (const float4*)(Hw + tid*128);
    for (int m4 = 0; m4 < 32; ++m4) {
        const float4 w = hwr[m4];
        acc += ul[m4*4]*w.x + ul[m4*4+1]*w.y + ul[m4*4+2]*w.z + ul[m4*4+3]*w.w;
    }
    const float r  = fmaxf(acc, 0.f);
    float y1 = r * a1v[b*128+tid];
    float y2 = r * a2v[b*128+tid];
    #pragma unroll
    for (int mask = 1; mask < 64; mask <<= 1) {
        y1 += __shfl_xor(y1, mask, 64);
        y2 += __shfl_xor(y2, mask, 64);
    }
    if ((tid & 63) == 0) { red1[tid>>6] = y1; red2[tid>>6] = y2; }
    __syncthreads();
    if (tid == 0) {
        const float z1 = red1[0] + red1[1];
        const float z2 = red2[0] + red2[1];
        const float mx = fmaxf(z1, z2);
        const float e1 = expf(z1-mx), e2 = expf(z2-mx);
        const float s  = e1 + e2;
        out[b*2+0] = e1 / s;
        out[b*2+1] = e2 / s;
    }
}

// ---------------------------------------------------------------- launch
extern "C" void kernel_launch(void* const* d_in, const int* in_sizes, int n_in,
                              void* d_out, int out_size, void* d_ws, size_t ws_size,
                              hipStream_t stream)
{
    const int*   ids  = (const int*)  d_in[0];
    const int*   ques = (const int*)  d_in[1];
    const int*   ans  = (const int*)  d_in[2];
    const float* E    = (const float*)d_in[3];
    const float* Uw   = (const float*)d_in[4];
    const float* Ubv  = (const float*)d_in[5];
    const float* Vw   = (const float*)d_in[6];
    const float* Vb   = (const float*)d_in[7];
    const float* Ww   = (const float*)d_in[8];
    const float* Wb   = (const float*)d_in[9];
    const float* sk   = (const float*)d_in[10];
    const float* Hw   = (const float*)d_in[11];
    const float* Hb   = (const float*)d_in[12];

    // workspace (floats): sT 1M | WsT 1M | vkey 2560 | qv/a1v/a2v 3*8192 | h 163840 | SK 163840
    float* ws   = (float*)d_ws;
    float* sT   = ws;
    float* WsT  = sT  + 1048576;
    float* vkey = WsT + 1048576;
    float* qv   = vkey + 2560;
    float* a1v  = qv  + 8192;
    float* a2v  = a1v + 8192;
    float* h    = a2v + 8192;
    float* SK   = h   + 163840;

    prep_kernel<<<1108, 128, 0, stream>>>(ids, ques, ans, E, Ww, Wb, Vw, Vb, sk,
                                          sT, WsT, vkey, qv, a1v, a2v, SK);
    scan_kernel<<<20, 512, 0, stream>>>(sT, WsT, vkey, Uw, Ubv, SK, h);
    final_kernel<<<64, 128, 0, stream>>>(h, qv, a1v, a2v, Hw, Hb, (float*)d_out);
}

// Round 10
// 380.301 us; speedup vs baseline: 1.8362x; 1.1756x over previous
//
#include <hip/hip_runtime.h>
#include <math.h>

// EntNet forward on MI355X.
// Sizes: VOC=32000, MEM=128, NSLOTS=20, NSENT=128, MAXLEN=32, QLEN=16, ANSLEN=8, B=64
//
// Register model (R2/3/4/8): per-wave budget = 512/(waves per SIMD), VGPR+AGPR
// combined; 512thr 1blk -> 256/wave. R9: top-of-step prefetch + rotation
// REGRESSED (346 vs R7 320) -> drain was already hidden; keep R7 placement.
//
// R10: state plane in LDS is PLAIN bf16 (row-major [64][136], stride 68 words
// == 4 mod 32 -> b128 reads at the 8-cyc floor, R5-proven). The fp32 recurrence
// accumulator xprev stays in registers, so per-step error enters only via the
// matmul/gate terms (~2^-8 of that term), not the state itself. Wins vs R7:
// A-frags 16->8 b128/wave (fragment-ready, ZERO v_perm), gate 4->2 b128,
// MFMA 24->16 (A*Wh + A*Wl, 2 indep chains), cheap pack. 2 barriers/step.

typedef __attribute__((ext_vector_type(8)))  short bf16x8;
typedef __attribute__((ext_vector_type(16))) float f32x16;

__device__ __forceinline__ unsigned short f2bh(float x) {   // f32 -> bf16 RNE
    unsigned int u = __float_as_uint(x);
    u += 0x7FFFu + ((u >> 16) & 1u);
    return (unsigned short)(u >> 16);
}
__device__ __forceinline__ float bh2f(unsigned short h) {
    return __uint_as_float(((unsigned int)h) << 16);
}
// u32 holding two bf16 (little-endian): low 16 = element 2i, high = 2i+1
__device__ __forceinline__ float blo(unsigned int w) { return __uint_as_float(w << 16); }
__device__ __forceinline__ float bhi(unsigned int w) { return __uint_as_float(w & 0xFFFF0000u); }

// ---------------------------------------------------------------- prep
__global__ __launch_bounds__(128) void prep_kernel(
    const int* __restrict__ ids, const int* __restrict__ ques, const int* __restrict__ ans,
    const float* __restrict__ E, const float* __restrict__ Ww, const float* __restrict__ Wb,
    const float* __restrict__ Vw, const float* __restrict__ Vb, const float* __restrict__ skeys,
    float* __restrict__ sT, float* __restrict__ WsT, float* __restrict__ vkey,
    float* __restrict__ qv, float* __restrict__ a1v, float* __restrict__ a2v,
    float* __restrict__ SK)
{
    const int bi  = blockIdx.x;
    const int tid = threadIdx.x;   // 128
    __shared__ float s_l[8][132];
    __shared__ float sk_l[20 * 132];
    __shared__ float k_l[128];
    if (bi < 1024) {
        const int b = bi >> 4;
        const int g = bi & 15;
        for (int r = tid; r < 2560; r += 128) sk_l[(r >> 7) * 132 + (r & 127)] = skeys[r];
        for (int tt = 0; tt < 8; ++tt) {
            const int t     = g * 8 + tt;
            const int token = ids[b * 4096 + t];
            const float v   = E[token * 128 + tid];
            s_l[tt][tid] = v;
            sT[(t * 64 + b) * 128 + tid] = v;         // layout (t, b, m)
        }
        __syncthreads();
        // Ws rows
        float acc[8];
        const float wbn = Wb[tid];
        #pragma unroll
        for (int i = 0; i < 8; ++i) acc[i] = wbn;
        const float4* wrow = (const float4*)(Ww + tid * 128);
        for (int m4 = 0; m4 < 32; ++m4) {
            const float4 w = wrow[m4];
            #pragma unroll
            for (int tt = 0; tt < 8; ++tt) {
                acc[tt] += s_l[tt][m4*4+0]*w.x + s_l[tt][m4*4+1]*w.y
                         + s_l[tt][m4*4+2]*w.z + s_l[tt][m4*4+3]*w.w;
            }
        }
        for (int tt = 0; tt < 8; ++tt)
            WsT[((g*8+tt) * 64 + b) * 128 + tid] = acc[tt];     // layout (t, b, n)
        // SK[j][t][b] = dot(s_t[b], skeys[j])  (gate key-dot, hoisted from scan)
        for (int idx = tid; idx < 160; idx += 128) {
            const int tt = idx / 20;
            const int jj = idx - tt * 20;
            float d = 0.f;
            for (int m = 0; m < 128; ++m) d += s_l[tt][m] * sk_l[jj * 132 + m];
            SK[(jj * 128 + (g*8 + tt)) * 64 + b] = d;
        }
    } else if (bi < 1044) {
        const int j = bi - 1024;
        k_l[tid] = skeys[j * 128 + tid];
        __syncthreads();
        float acc = Vb[tid];
        const float4* vrow = (const float4*)(Vw + tid * 128);
        for (int m4 = 0; m4 < 32; ++m4) {
            const float4 w = vrow[m4];
            acc += k_l[m4*4]*w.x + k_l[m4*4+1]*w.y + k_l[m4*4+2]*w.z + k_l[m4*4+3]*w.w;
        }
        vkey[j * 128 + tid] = acc;
    } else {
        const int b = bi - 1044;
        float sq = 0.f, s1 = 0.f, s2 = 0.f;
        for (int i = 0; i < 16; ++i) sq += E[ques[b*16+i] * 128 + tid];
        for (int i = 0; i < 8;  ++i) s1 += E[ans[(b*8+i)*2+0] * 128 + tid];
        for (int i = 0; i < 8;  ++i) s2 += E[ans[(b*8+i)*2+1] * 128 + tid];
        qv [b*128+tid] = sq * (1.f/16.f);
        a1v[b*128+tid] = s1 * 0.125f;
        a2v[b*128+tid] = s2 * 0.125f;
    }
}

// ---------------------------------------------------------------- scan (MFMA 32x32, bf16 state)
// One block per slot j. 512 threads = 8 waves, 2 waves/SIMD (256 regs/wave).
// Each wave owns ONE 32x32 C tile (bt2 = wave&1, nt2 = wave>>1).
//   Weights Wh/Wl (hi/lo bf16 of Uw) in 64 VGPRs, loaded once.
//   State AB: bf16[64][136] in LDS, fragment-ready (A-frag = 1 ds_read_b128/kc,
//     no perms). fp32 recurrence xprev[16] in registers carries full precision;
//     only the matmul/gate INPUT is rounded to bf16 each step.
//   2 MFMAs/kc (A*Wh + A*Wl), 2 independent chains by kc parity.
// C/D layout [m74/m101]: col = lane&31, row = (reg&3)+8*(reg>>2)+4*(lane>>5).
// Prefetch for t+1 in the update phase (R7-proven placement). 2 barriers/step.
__global__ __launch_bounds__(512, 1) void scan_kernel(
    const float* __restrict__ sT, const float* __restrict__ WsT,
    const float* __restrict__ vkey, const float* __restrict__ Uw,
    const float* __restrict__ Ub, const float* __restrict__ SK,
    float* __restrict__ h_out)
{
    __shared__ unsigned short AB[64 * 136];   // bf16 state, stride 136 (272B rows)
    __shared__ float g_l[64];
    __shared__ float wred[8];

    const int j    = blockIdx.x;
    const int tid  = threadIdx.x;        // 512
    const int wave = tid >> 6;           // 0..7
    const int lane = tid & 63;
    const int l32  = lane & 31;
    const int q    = lane >> 5;          // 0..1
    const int bt2  = wave & 1;           // b half
    const int nt2  = wave >> 1;          // n quarter
    const int n    = nt2 * 32 + l32;     // owned output column
    const int gb   = tid >> 3;           // gate: batch row 0..63
    const int gm   = (tid & 7) * 16;     // gate: m-slice (16 bf16)

    // ---- one-time: weight fragments -> 64 VGPRs ----
    bf16x8 b_h[8], b_l[8];
    {
        const int k0 = q * 8;
        #pragma unroll
        for (int kc = 0; kc < 8; ++kc) {
            const float4* src = (const float4*)(Uw + n * 128 + kc * 16 + k0);
            const float4 v0 = src[0], v1 = src[1];
            const float xs[8] = {v0.x,v0.y,v0.z,v0.w, v1.x,v1.y,v1.z,v1.w};
            #pragma unroll
            for (int e = 0; e < 8; ++e) {
                const unsigned short h = f2bh(xs[e]);
                b_h[kc][e] = (short)h;
                b_l[kc][e] = (short)f2bh(xs[e] - bh2f(h));
            }
        }
    }
    for (int i = tid; i < 64 * 136 / 2; i += 512) ((unsigned int*)AB)[i] = 0u;
    const float ubv = Ub[n] + vkey[j * 128 + n];

    // fp32 recurrence state (C layout), registers across steps
    float xprev[16];
    #pragma unroll
    for (int r = 0; r < 16; ++r) xprev[r] = 0.f;

    // ---- current-step globals (t = 0) ----
    float4 sv0, sv1, sv2, sv3;
    float  skv;
    float  wsv[16];
    {
        const float4* s4 = (const float4*)(sT + (0*64 + gb)*128 + gm);
        sv0 = s4[0]; sv1 = s4[1]; sv2 = s4[2]; sv3 = s4[3];
        skv = SK[(j*128 + 0)*64 + gb];
        #pragma unroll
        for (int r = 0; r < 16; ++r) {
            const int brow = bt2*32 + 4*q + (r & 3) + 8*(r >> 2);
            wsv[r] = WsT[(0*64 + brow)*128 + n];
        }
    }
    __syncthreads();

    float inv_s = 1.f;                   // true mem = inv_s * bf16(state)

    for (int t = 0; t < 128; ++t) {
        // ---- gate: g[b] = sigmoid(inv*dot(s_t[b],U[b]) + SK[j][t][b]) ----
        {
            const uint4* u4 = (const uint4*)(AB + gb * 136 + gm);   // 272B rows: aligned
            const uint4 w0 = u4[0], w1 = u4[1];                     // 16 bf16
            float d1 = sv0.x*blo(w0.x) + sv0.y*bhi(w0.x)
                     + sv0.z*blo(w0.y) + sv0.w*bhi(w0.y)
                     + sv1.x*blo(w0.z) + sv1.y*bhi(w0.z)
                     + sv1.z*blo(w0.w) + sv1.w*bhi(w0.w)
                     + sv2.x*blo(w1.x) + sv2.y*bhi(w1.x)
                     + sv2.z*blo(w1.y) + sv2.w*bhi(w1.y)
                     + sv3.x*blo(w1.z) + sv3.y*bhi(w1.z)
                     + sv3.z*blo(w1.w) + sv3.w*bhi(w1.w);
            d1 += __shfl_xor(d1, 1, 64);
            d1 += __shfl_xor(d1, 2, 64);
            d1 += __shfl_xor(d1, 4, 64);
            if ((tid & 7) == 0) g_l[gb] = 1.f / (1.f + expf(-(inv_s * d1 + skv)));
        }

        // ---- MFMA: acc = U(32b x 128m) . W(32n x 128m)^T, 2 indep chains ----
        f32x16 acc0 = {0.f,0.f,0.f,0.f,0.f,0.f,0.f,0.f,
                       0.f,0.f,0.f,0.f,0.f,0.f,0.f,0.f};
        f32x16 acc1 = acc0;
        {
            const unsigned short* arow = AB + (bt2*32 + l32) * 136 + q * 8;
            #pragma unroll
            for (int kc = 0; kc < 8; ++kc) {
                const bf16x8 a = *(const bf16x8*)(arow + kc * 16);   // fragment-ready
                if (kc & 1) {
                    acc1 = __builtin_amdgcn_mfma_f32_32x32x16_bf16(a, b_h[kc], acc1, 0, 0, 0);
                    acc1 = __builtin_amdgcn_mfma_f32_32x32x16_bf16(a, b_l[kc], acc1, 0, 0, 0);
                } else {
                    acc0 = __builtin_amdgcn_mfma_f32_32x32x16_bf16(a, b_h[kc], acc0, 0, 0, 0);
                    acc0 = __builtin_amdgcn_mfma_f32_32x32x16_bf16(a, b_l[kc], acc0, 0, 0, 0);
                }
            }
        }
        __syncthreads();   // B1: AB reads complete; g_l visible

        // ---- update owned (b, n) cells in C layout ----
        const float4 gA = *(const float4*)(g_l + bt2*32 + 4*q + 0);
        const float4 gB = *(const float4*)(g_l + bt2*32 + 4*q + 8);
        const float4 gC = *(const float4*)(g_l + bt2*32 + 4*q + 16);
        const float4 gD = *(const float4*)(g_l + bt2*32 + 4*q + 24);
        const float gr[16] = {gA.x,gA.y,gA.z,gA.w, gB.x,gB.y,gB.z,gB.w,
                              gC.x,gC.y,gC.z,gC.w, gD.x,gD.y,gD.z,gD.w};
        float ssq = 0.f;
        #pragma unroll
        for (int r = 0; r < 16; ++r) {
            const int brow = bt2*32 + 4*q + (r & 3) + 8*(r >> 2);
            float hr = fmaf(inv_s, acc0[r] + acc1[r], ubv + wsv[r]);
            hr = fmaxf(hr, 0.f);                          // h_cand
            const float x = fmaf(inv_s, xprev[r], gr[r] * hr);
            xprev[r] = x;                                 // fp32 recurrence
            AB[brow*136 + n] = f2bh(x);                   // bf16 matmul plane
            ssq = fmaf(x, x, ssq);
        }

        // ---- prefetch t+1 globals (R7 placement: overlaps shuffles + B2) ----
        {
            const int tn = (t < 127) ? t + 1 : 0;
            const float4* s4 = (const float4*)(sT + (tn*64 + gb)*128 + gm);
            sv0 = s4[0]; sv1 = s4[1]; sv2 = s4[2]; sv3 = s4[3];
            skv = SK[(j*128 + tn)*64 + gb];
            #pragma unroll
            for (int r = 0; r < 16; ++r) {
                const int brow = bt2*32 + 4*q + (r & 3) + 8*(r >> 2);
                wsv[r] = WsT[(tn*64 + brow)*128 + n];
            }
        }

        #pragma unroll
        for (int m = 1; m < 64; m <<= 1) ssq += __shfl_xor(ssq, m, 64);
        if (lane == 0) wred[wave] = ssq;
        __syncthreads();   // B2: AB writes + wred partials visible
        const float4 w0 = *(const float4*)(wred);
        const float4 w1 = *(const float4*)(wred + 4);
        inv_s = 1.f / sqrtf(w0.x+w0.y+w0.z+w0.w + w1.x+w1.y+w1.z+w1.w);
    }

    // ---- h = inv * state (fp32 path), layout (b, j, m) ----
    #pragma unroll
    for (int r = 0; r < 16; ++r) {
        const int brow = bt2*32 + 4*q + (r & 3) + 8*(r >> 2);
        h_out[(brow*20 + j)*128 + n] = inv_s * xprev[r];
    }
}

// ---------------------------------------------------------------- final
__global__ __launch_bounds__(128) void final_kernel(
    const float* __restrict__ h, const float* __restrict__ qv,
    const float* __restrict__ a1v, const float* __restrict__ a2v,
    const float* __restrict__ Hw, const float* __restrict__ Hb,
    float* __restrict__ out)
{
    const int b   = blockIdx.x;
    const int tid = threadIdx.x;    // 128
    __shared__ float hb[20][128];
    __shared__ float ql[128];
    __shared__ float ul[128];
    __shared__ float pl[20];
    __shared__ float lgt[20];
    __shared__ float red1[2], red2[2];

    for (int jj = 0; jj < 20; ++jj) hb[jj][tid] = h[(b*20+jj)*128 + tid];
    ql[tid] = qv[b*128 + tid];
    __syncthreads();
    if (tid < 20) {
        float d = 0.f;
        for (int m = 0; m < 128; ++m) d += hb[tid][m] * ql[m];
        lgt[tid] = d;
    }
    __syncthreads();
    if (tid == 0) {
        float mx = lgt[0];
        for (int jj = 1; jj < 20; ++jj) mx = fmaxf(mx, lgt[jj]);
        float s = 0.f;
        for (int jj = 0; jj < 20; ++jj) { const float e = expf(lgt[jj]-mx); pl[jj] = e; s += e; }
        const float is = 1.f / s;
        for (int jj = 0; jj < 20; ++jj) pl[jj] *= is;
    }
    __syncthreads();
    float u = 0.f;
    for (int jj = 0; jj < 20; ++jj) u += pl[jj] * hb[jj][tid];
    ul[tid] = u;
    __syncthreads();
    float acc = ql[tid] + Hb[tid];
    const float4* hwr = (const float4*)(Hw + tid*128);
    for (int m4 = 0; m4 < 32; ++m4) {
        const float4 w = hwr[m4];
        acc += ul[m4*4]*w.x + ul[m4*4+1]*w.y + ul[m4*4+2]*w.z + ul[m4*4+3]*w.w;
    }
    const float r  = fmaxf(acc, 0.f);
    float y1 = r * a1v[b*128+tid];
    float y2 = r * a2v[b*128+tid];
    #pragma unroll
    for (int mask = 1; mask < 64; mask <<= 1) {
        y1 += __shfl_xor(y1, mask, 64);
        y2 += __shfl_xor(y2, mask, 64);
    }
    if ((tid & 63) == 0) { red1[tid>>6] = y1; red2[tid>>6] = y2; }
    __syncthreads();
    if (tid == 0) {
        const float z1 = red1[0] + red1[1];
        const float z2 = red2[0] + red2[1];
        const float mx = fmaxf(z1, z2);
        const float e1 = expf(z1-mx), e2 = expf(z2-mx);
        const float s  = e1 + e2;
        out[b*2+0] = e1 / s;
        out[b*2+1] = e2 / s;
    }
}

// ---------------------------------------------------------------- launch
extern "C" void kernel_launch(void* const* d_in, const int* in_sizes, int n_in,
                              void* d_out, int out_size, void* d_ws, size_t ws_size,
                              hipStream_t stream)
{
    const int*   ids  = (const int*)  d_in[0];
    const int*   ques = (const int*)  d_in[1];
    const int*   ans  = (const int*)  d_in[2];
    const float* E    = (const float*)d_in[3];
    const float* Uw   = (const float*)d_in[4];
    const float* Ubv  = (const float*)d_in[5];
    const float* Vw   = (const float*)d_in[6];
    const float* Vb   = (const float*)d_in[7];
    const float* Ww   = (const float*)d_in[8];
    const float* Wb   = (const float*)d_in[9];
    const float* sk   = (const float*)d_in[10];
    const float* Hw   = (const float*)d_in[11];
    const float* Hb   = (const float*)d_in[12];

    // workspace (floats): sT 1M | WsT 1M | vkey 2560 | qv/a1v/a2v 3*8192 | h 163840 | SK 163840
    float* ws   = (float*)d_ws;
    float* sT   = ws;
    float* WsT  = sT  + 1048576;
    float* vkey = WsT + 1048576;
    float* qv   = vkey + 2560;
    float* a1v  = qv  + 8192;
    float* a2v  = a1v + 8192;
    float* h    = a2v + 8192;
    float* SK   = h   + 163840;

    prep_kernel<<<1108, 128, 0, stream>>>(ids, ques, ans, E, Ww, Wb, Vw, Vb, sk,
                                          sT, WsT, vkey, qv, a1v, a2v, SK);
    scan_kernel<<<20, 512, 0, stream>>>(sT, WsT, vkey, Uw, Ubv, SK, h);
    final_kernel<<<64, 128, 0, stream>>>(h, qv, a1v, a2v, Hw, Hb, (float*)d_out);
}